// Round 1
// baseline (245.631 us; speedup 1.0000x reference)
//
#include <hip/hip_runtime.h>
#include <hip/hip_bf16.h>
#include <stdint.h>

#define B_SZ 4
#define C_IN 256
#define N_SP 4096
#define HEADS 4
#define DH 32
#define HID 128

#define BI 128      // queries per block (4 waves x 32)
#define BJ 64       // keys per iteration
#define PP 68       // P LDS row pitch in shorts (136 B, 8B-aligned, ~2-way banks)

typedef short short4v __attribute__((ext_vector_type(4)));
typedef short short8 __attribute__((ext_vector_type(8)));
typedef float f32x4 __attribute__((ext_vector_type(4)));

#if __has_builtin(__builtin_amdgcn_exp2f)
#define EXP2 __builtin_amdgcn_exp2f
#else
#define EXP2 exp2f
#endif

__device__ __forceinline__ short f2bfs(float f) {  // round-half-up f32->bf16
  return (short)((__float_as_uint(f) + 0x8000u) >> 16);
}
__device__ __forceinline__ float bfs2f(short s) {  // bf16->f32
  return __uint_as_float(((uint32_t)(unsigned short)s) << 16);
}
__device__ __forceinline__ uint32_t pk_bf(float a, float b) {  // pack 2 bf16 (a=low)
  uint32_t ua = __float_as_uint(a) + 0x8000u;
  uint32_t ub = __float_as_uint(b) + 0x8000u;
  return (ua >> 16) | (ub & 0xffff0000u);
}
__device__ __forceinline__ short8 ld_frag(const short* p) {  // 8B-aligned 16B LDS read
  short4v a = *(const short4v*)p;
  short4v b = *(const short4v*)(p + 4);
  return __builtin_shufflevector(a, b, 0, 1, 2, 3, 4, 5, 6, 7);
}
__device__ __forceinline__ f32x4 mfma16(short8 a, short8 b, f32x4 c) {
  return __builtin_amdgcn_mfma_f32_16x16x32_bf16(a, b, c, 0, 0, 0);
}

// ---------------- Kernel 0: prep — transpose+split x -> bf16 hi/lo [b][n][c];
// convert w_qkv / w_out -> bf16 hi/lo ([o][c], k-contiguous).
__global__ __launch_bounds__(256) void prep_k(
    const float* __restrict__ x, const float* __restrict__ w_qkv,
    const float* __restrict__ w_out,
    short* __restrict__ xh, short* __restrict__ xl,
    short* __restrict__ wqh, short* __restrict__ wql,
    short* __restrict__ woh, short* __restrict__ wol) {
  const int t = threadIdx.x;
  const int bx = blockIdx.x;
  if (bx < 256) {  // x transpose blocks: 64 n x 256 c per block
    __shared__ float T[64 * 65];  // [n][c-chunk], pitch 65 (2-way banks = free)
    const int b = bx >> 6, n0 = (bx & 63) * 64;
    const float* xb = x + (size_t)b * C_IN * N_SP;
    for (int c0 = 0; c0 < C_IN; c0 += 64) {
      {  // read 64c x 64n coalesced (wave reads 64 consecutive n at fixed c)
        const int n = t & 63, cw = t >> 6;
#pragma unroll
        for (int i = 0; i < 16; ++i) {
          const int c = cw * 16 + i;
          T[n * 65 + c] = xb[(size_t)(c0 + c) * N_SP + n0 + n];
        }
      }
      __syncthreads();
      {  // write hi/lo rows [n][c]: 16B stores, 4 lanes cover 32B/row
        const int n = t >> 2, cg = t & 3;
#pragma unroll
        for (int j = 0; j < 2; ++j) {
          const int c = cg * 16 + j * 8;
          short8 hv, lv;
#pragma unroll
          for (int e = 0; e < 8; ++e) {
            const float v = T[n * 65 + c + e];
            const short hh = f2bfs(v);
            hv[e] = hh;
            lv[e] = f2bfs(v - bfs2f(hh));
          }
          const size_t off = ((size_t)(b * N_SP + n0 + n)) * C_IN + c0 + c;
          *(short8*)(xh + off) = hv;
          *(short8*)(xl + off) = lv;
        }
      }
      __syncthreads();
    }
  } else {  // weight blocks: flat convert 131072 floats (boundary at block 256+12)
    const int f0 = (bx - 256) * 8192;
#pragma unroll
    for (int j = 0; j < 32; ++j) {
      const int f = f0 + j * 256 + t;
      float v;
      short *dh, *dl;
      int idx;
      if (f < 384 * 256) { v = w_qkv[f]; dh = wqh; dl = wql; idx = f; }
      else { idx = f - 384 * 256; v = w_out[idx]; dh = woh; dl = wol; }
      const short hh = f2bfs(v);
      dh[idx] = hh;
      dl[idx] = f2bfs(v - bfs2f(hh));
    }
  }
}

// ---------------- Kernel 1: QKV projection, bf16x3 MFMA ----------------
// grid (64 ntiles, 3 osec, 4 b); wave = 16 n, 128 o (8 o-tiles).
// osec 0/1 (q/k): D[o][n] -> qt/kt [bh][n][d] (scale*log2e folded into q).
// osec 2 (v): swapped operands -> D[n][o] -> vt [bh][d][n].
__global__ __launch_bounds__(256) void qkv_mfma_k(
    const short* __restrict__ xh, const short* __restrict__ xl,
    const short* __restrict__ wqh, const short* __restrict__ wql,
    short* __restrict__ qt, short* __restrict__ kt, short* __restrict__ vt) {
  const int t = threadIdx.x;
  const int lane = t & 63, w = t >> 6;
  const int l15 = lane & 15, quad = lane >> 4;
  const int osec = blockIdx.y, b = blockIdx.z;
  const int n0 = blockIdx.x * 64 + w * 16;
  const size_t xrow = ((size_t)(b * N_SP + n0 + l15)) * C_IN;
  const size_t wrow = ((size_t)(osec * 128 + l15)) * C_IN;
  const bool isv = (osec == 2);
  const f32x4 zz = {0.f, 0.f, 0.f, 0.f};
  f32x4 acc[8];
#pragma unroll
  for (int ot = 0; ot < 8; ++ot) acc[ot] = zz;

  for (int k0 = 0; k0 < C_IN; k0 += 32) {
    const int ko = k0 + quad * 8;
    const short8 xhf = *(const short8*)(xh + xrow + ko);
    const short8 xlf = *(const short8*)(xl + xrow + ko);
#pragma unroll
    for (int ot = 0; ot < 8; ++ot) {
      const size_t wo = wrow + (size_t)ot * 16 * C_IN + ko;
      const short8 whf = *(const short8*)(wqh + wo);
      const short8 wlf = *(const short8*)(wql + wo);
      if (isv) {  // A = x (rows n), B = w (rows o)
        acc[ot] = mfma16(xhf, whf, acc[ot]);
        acc[ot] = mfma16(xlf, whf, acc[ot]);
        acc[ot] = mfma16(xhf, wlf, acc[ot]);
      } else {    // A = w (rows o), B = x (rows n)
        acc[ot] = mfma16(whf, xhf, acc[ot]);
        acc[ot] = mfma16(whf, xlf, acc[ot]);
        acc[ot] = mfma16(wlf, xhf, acc[ot]);
      }
    }
  }

  if (!isv) {  // lane holds o = osec*128 + ot*16 + quad*4 + r, n = n0 + l15
    const float sc = osec ? 1.f : (0.17677669529663687f * 1.4426950408889634f);
    short* dst = osec ? kt : qt;
    const int n = n0 + l15;
#pragma unroll
    for (int ot = 0; ot < 8; ++ot) {
      const int ol = ot * 16 + quad * 4;
      const int h = ol >> 5, d0 = ol & 31;
      short4v p;
#pragma unroll
      for (int r = 0; r < 4; ++r) p[r] = f2bfs(acc[ot][r] * sc);
      *(short4v*)(dst + ((size_t)(b * HEADS + h) * N_SP + n) * DH + d0) = p;
    }
  } else {     // lane holds n = n0 + quad*4 + r, o = 256 + ot*16 + l15
    const int n = n0 + quad * 4;
#pragma unroll
    for (int ot = 0; ot < 8; ++ot) {
      const int ol = ot * 16 + l15;
      const int h = ol >> 5, d = ol & 31;
      short4v p;
#pragma unroll
      for (int r = 0; r < 4; ++r) p[r] = f2bfs(acc[ot][r]);
      *(short4v*)(vt + ((size_t)(b * HEADS + h) * DH + d) * N_SP + n) = p;
    }
  }
}

// ---------------- Kernel 2: flash attention, bf16 MFMA (unchanged core) -------
// Epilogue now emits att as bf16 hi/lo in [b][n][hid] (k-contiguous for out GEMM).
__global__ __launch_bounds__(256, 2) void attn_k(
    const short* __restrict__ qt, const short* __restrict__ kt,
    const short* __restrict__ vt, short* __restrict__ ath,
    short* __restrict__ atl) {
  __shared__ short Ps[BI * PP];     // 17408 B, [i][j] bf16, rows owned per-wave
  __shared__ float Osh[DH * 132];   // 16896 B, epilogue transpose
  const int t = threadIdx.x;
  const int lane = t & 63, w = t >> 6;
  const int l15 = lane & 15, quad = lane >> 4;
  const int i0 = blockIdx.x * BI;
  const int bh = blockIdx.y;
  const short* qg = qt + ((size_t)bh * N_SP + i0) * DH;
  const short* kg = kt + (size_t)bh * N_SP * DH;
  const short* vg = vt + (size_t)bh * DH * N_SP;

  // Q fragments (loop-invariant): B[n=i][k=d]
  short8 bq[2];
#pragma unroll
  for (int tt = 0; tt < 2; ++tt)
    bq[tt] = *(const short8*)(qg + (size_t)(w * 32 + tt * 16 + l15) * DH + quad * 8);

  const f32x4 zz = {0.f, 0.f, 0.f, 0.f};
  f32x4 o_acc[2][2] = {{zz, zz}, {zz, zz}};  // [tt][dt]
  float lsum[2] = {0.f, 0.f};
  short* prow[2];
#pragma unroll
  for (int tt = 0; tt < 2; ++tt) prow[tt] = Ps + (w * 32 + tt * 16 + l15) * PP;

  short8 akA[4], akB[4], vbA[2][2], vbB[2][2];
#pragma unroll
  for (int jt = 0; jt < 4; ++jt)
    akA[jt] = *(const short8*)(kg + (size_t)(jt * 16 + l15) * DH + quad * 8);
#pragma unroll
  for (int dt = 0; dt < 2; ++dt)
#pragma unroll
    for (int kk = 0; kk < 2; ++kk)
      vbA[dt][kk] = *(const short8*)(vg + (size_t)(dt * 16 + l15) * N_SP + kk * 32 + quad * 8);

  auto body = [&](const short8 (&akc)[4], const short8 (&vbc)[2][2],
                  short8 (&akn)[4], short8 (&vbn)[2][2], int jn) {
    // S^T tiles: D[j][i] = mfma(K, Q)
    f32x4 sf[2][4];
#pragma unroll
    for (int tt = 0; tt < 2; ++tt)
#pragma unroll
      for (int jt = 0; jt < 4; ++jt) sf[tt][jt] = mfma16(akc[jt], bq[tt], zz);
    // prefetch next tile's K/V into the alternate register set
#pragma unroll
    for (int jt = 0; jt < 4; ++jt)
      akn[jt] = *(const short8*)(kg + (size_t)(jn + jt * 16 + l15) * DH + quad * 8);
#pragma unroll
    for (int dt = 0; dt < 2; ++dt)
#pragma unroll
      for (int kk = 0; kk < 2; ++kk)
        vbn[dt][kk] = *(const short8*)(vg + (size_t)(dt * 16 + l15) * N_SP + jn + kk * 32 + quad * 8);
    // exp2 (no max), accumulate l, pack P[i][j]
#pragma unroll
    for (int tt = 0; tt < 2; ++tt)
#pragma unroll
      for (int jt = 0; jt < 4; ++jt) {
        const float e0 = EXP2(sf[tt][jt][0]);
        const float e1 = EXP2(sf[tt][jt][1]);
        const float e2 = EXP2(sf[tt][jt][2]);
        const float e3 = EXP2(sf[tt][jt][3]);
        lsum[tt] += (e0 + e1) + (e2 + e3);
        uint2 pk; pk.x = pk_bf(e0, e1); pk.y = pk_bf(e2, e3);
        *(uint2*)(prow[tt] + jt * 16 + quad * 4) = pk;
      }
    asm volatile("s_waitcnt lgkmcnt(0)" ::: "memory");  // same-wave P write->read
    // O += P V^T
    short8 pa[2][2];
#pragma unroll
    for (int tt = 0; tt < 2; ++tt)
#pragma unroll
      for (int kk = 0; kk < 2; ++kk) pa[tt][kk] = ld_frag(prow[tt] + kk * 32 + quad * 8);
#pragma unroll
    for (int tt = 0; tt < 2; ++tt)
#pragma unroll
      for (int dt = 0; dt < 2; ++dt) {
        o_acc[tt][dt] = mfma16(pa[tt][0], vbc[dt][0], o_acc[tt][dt]);
        o_acc[tt][dt] = mfma16(pa[tt][1], vbc[dt][1], o_acc[tt][dt]);
      }
  };

  for (int jt0 = 0; jt0 < N_SP; jt0 += 2 * BJ) {
    body(akA, vbA, akB, vbB, (jt0 + BJ) & (N_SP - 1));
    body(akB, vbB, akA, vbA, (jt0 + 2 * BJ) & (N_SP - 1));
  }

  // finalize l: reduce over quads (lanes sharing l15)
#pragma unroll
  for (int tt = 0; tt < 2; ++tt) {
    lsum[tt] += __shfl_xor(lsum[tt], 16);
    lsum[tt] += __shfl_xor(lsum[tt], 32);
  }
  float linv[2][4];
#pragma unroll
  for (int tt = 0; tt < 2; ++tt)
#pragma unroll
    for (int r = 0; r < 4; ++r) linv[tt][r] = 1.f / __shfl(lsum[tt], quad * 4 + r);
  // normalize + transpose to Osh[d][i]
#pragma unroll
  for (int tt = 0; tt < 2; ++tt)
#pragma unroll
    for (int dt = 0; dt < 2; ++dt)
#pragma unroll
      for (int r = 0; r < 4; ++r)
        Osh[(dt * 16 + l15) * 132 + w * 32 + tt * 16 + quad * 4 + r] =
            o_acc[tt][dt][r] * linv[tt][r];
  __syncthreads();
  {  // emit att bf16 hi/lo in [b][n][hid]: thread owns (row ii, 16-d half)
    const int ii = t & 127, half = t >> 7;
    const int b = bh >> 2, h = bh & 3;
#pragma unroll
    for (int j = 0; j < 2; ++j) {
      short8 hv, lv;
#pragma unroll
      for (int e = 0; e < 8; ++e) {
        const int d = half * 16 + j * 8 + e;
        const float v = Osh[d * 132 + ii];
        const short hh = f2bfs(v);
        hv[e] = hh;
        lv[e] = f2bfs(v - bfs2f(hh));
      }
      const size_t off =
          ((size_t)(b * N_SP + i0 + ii)) * HID + h * 32 + half * 16 + j * 8;
      *(short8*)(ath + off) = hv;
      *(short8*)(atl + off) = lv;
    }
  }
}

// ---------------- Kernel 3: output projection + bias, bf16x3 MFMA ----------------
// grid (64 ntiles, 2 osec, 4 b); wave = 16 n, 128 o. Swapped operands:
// A = att (rows n), B = w_out (rows o) -> lane holds 4 consecutive n -> float4 store.
__global__ __launch_bounds__(256) void out_mfma_k(
    const short* __restrict__ ath, const short* __restrict__ atl,
    const short* __restrict__ woh, const short* __restrict__ wol,
    const float* __restrict__ bias, float* __restrict__ out) {
  const int t = threadIdx.x;
  const int lane = t & 63, w = t >> 6;
  const int l15 = lane & 15, quad = lane >> 4;
  const int osec = blockIdx.y, b = blockIdx.z;
  const int n0 = blockIdx.x * 64 + w * 16;
  const size_t arow = ((size_t)(b * N_SP + n0 + l15)) * HID;
  const size_t wrow = ((size_t)(osec * 128 + l15)) * HID;
  const f32x4 zz = {0.f, 0.f, 0.f, 0.f};
  f32x4 acc[8];
#pragma unroll
  for (int ot = 0; ot < 8; ++ot) acc[ot] = zz;

  for (int k0 = 0; k0 < HID; k0 += 32) {
    const int ko = k0 + quad * 8;
    const short8 ahf = *(const short8*)(ath + arow + ko);
    const short8 alf = *(const short8*)(atl + arow + ko);
#pragma unroll
    for (int ot = 0; ot < 8; ++ot) {
      const size_t wo = wrow + (size_t)ot * 16 * HID + ko;
      const short8 whf = *(const short8*)(woh + wo);
      const short8 wlf = *(const short8*)(wol + wo);
      acc[ot] = mfma16(ahf, whf, acc[ot]);
      acc[ot] = mfma16(alf, whf, acc[ot]);
      acc[ot] = mfma16(ahf, wlf, acc[ot]);
    }
  }
  // lane holds n = n0 + quad*4 + r, o = osec*128 + ot*16 + l15
#pragma unroll
  for (int ot = 0; ot < 8; ++ot) {
    const int o = osec * 128 + ot * 16 + l15;
    const float bv = bias[o];
    float4 v = make_float4(acc[ot][0] + bv, acc[ot][1] + bv,
                           acc[ot][2] + bv, acc[ot][3] + bv);
    *(float4*)(out + ((size_t)(b * C_IN + o)) * N_SP + n0 + quad * 4) = v;
  }
}

extern "C" void kernel_launch(void* const* d_in, const int* in_sizes, int n_in,
                              void* d_out, int out_size, void* d_ws, size_t ws_size,
                              hipStream_t stream) {
  const float* x = (const float*)d_in[0];
  const float* w_qkv = (const float*)d_in[1];
  const float* w_out = (const float*)d_in[2];
  const float* b_out = (const float*)d_in[3];
  float* out = (float*)d_out;

  // workspace layout (bf16 shorts), ~28.5 MiB total:
  short* xh = (short*)d_ws;                         // 4*4096*256 = 8.39 MB
  short* xl = xh + (size_t)B_SZ * N_SP * C_IN;      // 8.39 MB
  short* wqh = xl + (size_t)B_SZ * N_SP * C_IN;     // 384*256*2B
  short* wql = wqh + 384 * C_IN;
  short* woh = wql + 384 * C_IN;                    // 256*128*2B
  short* wol = woh + C_IN * HID;
  short* qt = wol + C_IN * HID;                     // 16*4096*32 = 4 MB
  short* kt = qt + (size_t)16 * N_SP * DH;          // 4 MB
  short* vt = kt + (size_t)16 * N_SP * DH;          // 4 MB
  short* ath = xh;                                  // alias: xh/xl dead after qkv_mfma
  short* atl = ath + (size_t)B_SZ * N_SP * HID;     // both fit exactly in xh region

  prep_k<<<dim3(272), 256, 0, stream>>>(x, w_qkv, w_out, xh, xl, wqh, wql, woh, wol);
  qkv_mfma_k<<<dim3(64, 3, B_SZ), 256, 0, stream>>>(xh, xl, wqh, wql, qt, kt, vt);
  attn_k<<<dim3(N_SP / BI, B_SZ * HEADS), 256, 0, stream>>>(qt, kt, vt, ath, atl);
  out_mfma_k<<<dim3(64, 2, B_SZ), 256, 0, stream>>>(ath, atl, woh, wol, b_out, out);
}